// Round 12
// baseline (291.913 us; speedup 1.0000x reference)
//
#include <hip/hip_runtime.h>
#include <cstdint>
#include <cstddef>

// ---------------------------------------------------------------------------
// NaiveSDPA: out[n,s,v] = softmax(Q·K^T / 8 + mask) · V ; f32 I/O, bf16 MFMA.
// v17: same 16 waves/CU, 2x the barrier groups.
// Ledger r0-r11 (6 spill events): the 64-reg tier is unreachable for this
// loop (even ~58-reg working sets spill at the 64 budget); 16 waves/CU is
// the register-law ceiling. r11 verified the K-image XOR swizzle
// (conflicts 2.2e7 -> 1.36e7, fwd 197 -> 190us).
// v17 re-shapes the SAME wave count: 256-thr blocks (4 waves x 16q, BQ=64),
// grid (64,16) = 1024 blocks -> 4 blocks/CU (LDS 4x34.8=139KB<=160,
// thr 1024, launch_bounds(256,4) = 128-reg budget for a ~40-reg kernel —
// NO tier forcing, zero spill risk). Each SIMD: 4 waves from 4 INDEPENDENT
// barrier groups (was 2 groups of 8) -> barrier/vmcnt drains idle 1/4 of
// the CU instead of 1/2. Cost: tile DMA bytes double (~1.1GB from L2/L3,
// ~7 TB/s aggregate << 34.5 TB/s L2 ceiling; HBM untouched).
// Diagnostic: fwd -20-40us => barrier-group wall confirmed; fwd ~190 =>
// per-wave dependency chain is the wall (next: in-loop pipelining).
// Split/atomic/combine machinery deleted (single pass).
// ---------------------------------------------------------------------------

typedef __attribute__((ext_vector_type(8))) short short8;
typedef __attribute__((ext_vector_type(4))) short short4v;
typedef __attribute__((ext_vector_type(4))) float f32x4;
typedef __attribute__((ext_vector_type(4))) unsigned int uint4v;
typedef __attribute__((ext_vector_type(2))) unsigned int uint2v;

#define DEV __device__ __forceinline__

constexpr int N_B   = 16;
constexpr int S_Q   = 4096;
constexpr int S_KV  = 4096;
constexpr int DH    = 64;
constexpr int BQ    = 64;          // q rows per block (4 waves x 16)
constexpr int BK    = 64;
constexpr int ITERS = S_KV / BK;   // 64 tiles
constexpr int KROW  = 64;          // shorts/K-row: 128B, XOR-swizzled chunks
constexpr int VSTR  = 68;          // shorts/V^T-row: 136B (16 slots + pad)
constexpr int KIMG_B = 8192;       // K tile image bytes (64 x 128B)
constexpr int VIMG_B = 9216;       // V tile image bytes (8704 + 512 pad)
constexpr int TILE_B = KIMG_B + VIMG_B;   // 17408

#define LOG2E 1.44269504088896340736f
#define QSCALE (0.125f * 1.44269504088896340736f)   // fold /8 + log2e into Q

DEV unsigned short f2bf(float f) {           // RNE f32 -> bf16
  union { float f; unsigned int i; } x; x.f = f;
  unsigned int r = x.i + 0x7FFFu + ((x.i >> 16) & 1u);
  return (unsigned short)(r >> 16);
}

#if __has_builtin(__builtin_amdgcn_cvt_pk_bf16_f32)
typedef __attribute__((ext_vector_type(2))) __bf16 bf16x2v;
DEV unsigned int packrne(float a, float b) {   // bf16(a) lo | bf16(b) hi, RNE
  union { bf16x2v v; unsigned int u; } x;
  x.v = __builtin_amdgcn_cvt_pk_bf16_f32(a, b);
  return x.u;
}
#else
DEV unsigned int packrne(float a, float b) {
  union { float f; unsigned int u; } ua, ub; ua.f = a; ub.f = b;
  unsigned int ra = ua.u + 0x7FFFu + ((ua.u >> 16) & 1u);
  unsigned int rb = ub.u + 0x7FFFu + ((ub.u >> 16) & 1u);
  return __builtin_amdgcn_perm(rb, ra, 0x07060302u);
}
#endif

DEV f32x4 mfma16(short4v a, short4v b, f32x4 c) {
#if __has_builtin(__builtin_amdgcn_mfma_f32_16x16x16bf16_1k)
  return __builtin_amdgcn_mfma_f32_16x16x16bf16_1k(a, b, c, 0, 0, 0);
#elif __has_builtin(__builtin_amdgcn_mfma_f32_16x16x16_bf16)
  return __builtin_amdgcn_mfma_f32_16x16x16_bf16(a, b, c, 0, 0, 0);
#else
  asm volatile("v_mfma_f32_16x16x16_bf16 %0, %1, %2, %0\n\ts_nop 7\n\ts_nop 7"
               : "+v"(c) : "v"(a), "v"(b));
  return c;
#endif
}

// stage K tile image (256 threads): thread tS owns rows r0=tS>>3 and r0+32,
// chunk c=tS&7, stored at (c ^ (row&7))*16B on 128B rows (r11-verified).
DEV void stageK(unsigned short* buf, const f32x4* L, int tS) {
  const int r0 = tS >> 3, c = tS & 7;
  const int cs = (c ^ (r0 & 7)) * 8;          // shorts
  uint4v d0, d1;
  d0[0] = packrne(L[0][0], L[0][1]); d0[1] = packrne(L[0][2], L[0][3]);
  d0[2] = packrne(L[1][0], L[1][1]); d0[3] = packrne(L[1][2], L[1][3]);
  d1[0] = packrne(L[2][0], L[2][1]); d1[1] = packrne(L[2][2], L[2][3]);
  d1[2] = packrne(L[3][0], L[3][1]); d1[3] = packrne(L[3][2], L[3][3]);
  *(uint4v*)&buf[r0 * KROW + cs]        = d0;
  *(uint4v*)&buf[(r0 + 32) * KROW + cs] = d1;
}

// stage V^T tile image (256 threads): chunk a=tS>>4 of vcol=4x+j (x=tS&15)
// at slot (a+x)&15 on 136B rows (conflict-verified pattern).
DEV void stageV(unsigned short* buf, const f32x4* L, int tS) {
  const int a = tS >> 4;
  const int x = tS & 15;
  const int slot = (a + x) & 15;
#pragma unroll
  for (int j = 0; j < 4; ++j) {
    uint2v d;
    d[0] = packrne(L[0][j], L[1][j]);
    d[1] = packrne(L[2][j], L[3][j]);
    *(uint2v*)&buf[(x * 4 + j) * VSTR + slot * 4] = d;
  }
}

// async 16B global->LDS DMA
DEV void dma16(const void* g, void* l) {
#if __has_builtin(__builtin_amdgcn_global_load_lds)
  __builtin_amdgcn_global_load_lds(
      (const __attribute__((address_space(1))) unsigned int*)g,
      (__attribute__((address_space(3))) unsigned int*)l, 16, 0, 0);
#else
  ((uint4v*)l)[threadIdx.x & 63] = *(const uint4v*)g;
#endif
}

// 4-wave tile DMA: K image 8KB = 8x1KB (wave w takes chunks w, w+4),
// V image 9216B = 9x1KB (wave w takes chunks w, w+4; wave 0 takes chunk 8).
// All LDS bases wave-uniform + lane*16 (HW requirement).
DEV void dmaTile4w(const char* gt, char* lk, char* lv, int w, int laneB) {
  const int b0 = w * 1024;
  dma16(gt + b0 + laneB,        lk + b0);
  dma16(gt + b0 + 4096 + laneB, lk + b0 + 4096);
  const char* gv = gt + KIMG_B;
  dma16(gv + b0 + laneB,        lv + b0);
  dma16(gv + b0 + 4096 + laneB, lv + b0 + 4096);
  if (w == 0) dma16(gv + 8192 + laneB, lv + 8192);
}

// ---- prep: build per-(n,tile) bf16 LDS images in workspace (~13us)
__global__ __launch_bounds__(256)
void sdpa_prep(const float* __restrict__ Kg, const float* __restrict__ Vg,
               unsigned short* __restrict__ imgs) {
  const int b   = blockIdx.x;           // n*64 + tau
  const int n   = b >> 6, tau = b & 63;
  const int tS  = threadIdx.x;
  unsigned short* img = imgs + (size_t)b * (TILE_B / 2);
  {
    const float* kp =
        Kg + ((size_t)n * S_KV + tau * 64 + (tS >> 3)) * DH + (tS & 7) * 8;
    f32x4 L[4];
    L[0] = *(const f32x4*)(kp);
    L[1] = *(const f32x4*)(kp + 4);
    L[2] = *(const f32x4*)(kp + 32 * DH);
    L[3] = *(const f32x4*)(kp + 32 * DH + 4);
    stageK(img, L, tS);
  }
  {
    const float* vp =
        Vg + ((size_t)n * S_KV + tau * 64 + (size_t)(tS >> 4) * 4) * DH
           + (tS & 15) * 4;
    f32x4 L[4];
#pragma unroll
    for (int i = 0; i < 4; ++i) L[i] = *(const f32x4*)(vp + i * DH);
    stageV(img + KIMG_B / 2, L, tS);
  }
}

// ---- main: 256-thr, 4 waves x 16q, 4 blocks/CU (4 barrier groups/CU)
__global__ __launch_bounds__(256, 4)
void sdpa_fwd4(const float* __restrict__ Qg,
               const float* __restrict__ Mg,
               const unsigned short* __restrict__ imgs,
               float* __restrict__ Og)
{
  __shared__ __align__(16) unsigned short ldsK[2][KIMG_B / 2];  // 2 x 8192 B
  __shared__ __align__(16) unsigned short ldsV[2][VIMG_B / 2];  // 2 x 9216 B

  const int n     = blockIdx.y;
  const int q0    = blockIdx.x * BQ;
  const int t     = threadIdx.x;
  const int w     = t >> 6;                 // wave 0..3: q rows q0+16w..+15
  const int lane  = t & 63;
  const int l15   = lane & 15;
  const int quad  = lane >> 4;
  const int qrow  = q0 + w * 16 + l15;
  const int laneB = lane * 16;
  const int tbase = n * 64;

  // Q B-frags, pre-scaled by 0.125*log2e (softmax scale-invariant)
  short8 qf0, qf1;
  {
    const float* qp = Qg + ((size_t)n * S_Q + (size_t)qrow) * DH + quad * 8;
#pragma unroll
    for (int j = 0; j < 8; ++j) {
      qf0[j] = (short)f2bf(qp[j] * QSCALE);
      qf1[j] = (short)f2bf(qp[32 + j] * QSCALE);
    }
  }

  const float* mrow = Mg + (size_t)qrow * S_KV + quad * 4;

  // swizzled kf chunk offsets (shorts): chunk = (quad|quad+4) ^ (l15&7)
  const int swz = l15 & 7;
  const int c0 = (quad ^ swz) * 8;
  const int c1 = ((quad + 4) ^ swz) * 8;

  f32x4 acc[4];
#pragma unroll
  for (int nt = 0; nt < 4; ++nt)
#pragma unroll
    for (int r = 0; r < 4; ++r) acc[nt][r] = 0.0f;
  float rs = 0.0f;

  dmaTile4w((const char*)imgs + (size_t)tbase * TILE_B,
            (char*)&ldsK[0][0], (char*)&ldsV[0][0], w, laneB);
  __syncthreads();

  for (int it = 0; it < ITERS; ++it) {
    const int p   = it & 1;
    const int kv0 = it * BK;
    const bool more = (it + 1 < ITERS);

    // issue next-tile DMA first: covered by the whole compute phase
    if (more)
      dmaTile4w((const char*)imgs + (size_t)(tbase + it + 1) * TILE_B,
                (char*)&ldsK[p ^ 1][0], (char*)&ldsV[p ^ 1][0], w, laneB);

    const unsigned short* kb = &ldsK[p][l15 * KROW];

    // phase 1: per-h { kf read, mask load, QK MFMA, exp, rs, pack }
    short4v pf[4];
#pragma unroll
    for (int h = 0; h < 4; ++h) {
      const short8 kf0 = *(const short8*)(kb + h * 1024 + c0);
      const short8 kf1 = *(const short8*)(kb + h * 1024 + c1);
      const f32x4 mk = *(const f32x4*)(mrow + kv0 + 16 * h);
      f32x4 c = {0.f, 0.f, 0.f, 0.f};
      __builtin_amdgcn_s_setprio(1);
      c = __builtin_amdgcn_mfma_f32_16x16x32_bf16(kf0, qf0, c, 0, 0, 0);
      c = __builtin_amdgcn_mfma_f32_16x16x32_bf16(kf1, qf1, c, 0, 0, 0);
      __builtin_amdgcn_s_setprio(0);
      float e[4];
#pragma unroll
      for (int r = 0; r < 4; ++r)
        e[r] = __builtin_amdgcn_exp2f(fmaf(mk[r], LOG2E, c[r]));
      rs += (e[0] + e[1]) + (e[2] + e[3]);
      union { uint2v u; short4v s; } ue;
      ue.u[0] = packrne(e[0], e[1]);
      ue.u[1] = packrne(e[2], e[3]);
      pf[h] = ue.s;
    }

    // PV: O^T += V^T·P^T
    __builtin_amdgcn_s_setprio(1);
#pragma unroll
    for (int nt = 0; nt < 4; ++nt) {
      const int vcol = l15 + 16 * nt;
      const int xr   = (l15 >> 2) + 4 * nt;
#pragma unroll
      for (int h = 0; h < 4; ++h) {
        const int slot = ((4 * h + quad) + xr) & 15;
        short4v vf = *(const short4v*)&ldsV[p][vcol * VSTR + slot * 4];
        acc[nt] = mfma16(vf, pf[h], acc[nt]);
      }
    }
    __builtin_amdgcn_s_setprio(0);

    __syncthreads();   // drains DMA + orders buffer reuse
  }

  // epilogue: single cross-quad reduce; coalesced f32x4 stores
  rs += __shfl_xor(rs, 16, 64);
  rs += __shfl_xor(rs, 32, 64);
  const float inv = 1.0f / rs;
  float* ob = Og + ((size_t)n * S_Q + (size_t)qrow) * DH + quad * 4;
#pragma unroll
  for (int nt = 0; nt < 4; ++nt) {
    f32x4 o;
#pragma unroll
    for (int r = 0; r < 4; ++r) o[r] = acc[nt][r] * inv;
    *(f32x4*)(ob + 16 * nt) = o;
  }
}

// ---- fallback: reg-staging single-pass (r8-proven structure, swizzled K)
__global__ __launch_bounds__(512, 4)
void sdpa_fwd_reg(const float* __restrict__ Qg, const float* __restrict__ Kg,
                  const float* __restrict__ Vg, const float* __restrict__ Mg,
                  float* __restrict__ Og)
{
  __shared__ __align__(16) unsigned short ldsK[2][KIMG_B / 2];
  __shared__ __align__(16) unsigned short ldsV[2][VIMG_B / 2];

  const int n = blockIdx.y, q0 = blockIdx.x * 128, t = threadIdx.x;
  const int w = t >> 6, lane = t & 63, l15 = lane & 15, quad = lane >> 4;
  const int qrow = q0 + w * 16 + l15;

  short8 qf0, qf1;
  {
    const float* qp = Qg + ((size_t)n * S_Q + (size_t)qrow) * DH + quad * 8;
#pragma unroll
    for (int j = 0; j < 8; ++j) {
      qf0[j] = (short)f2bf(qp[j] * QSCALE);
      qf1[j] = (short)f2bf(qp[32 + j] * QSCALE);
    }
  }
  const bool isK = (w < 4);
  const int  tS  = t & 255;
  const float* sgp =
      isK ? Kg + ((size_t)n * S_KV + (size_t)(tS >> 3)) * DH + (tS & 7) * 8
          : Vg + ((size_t)n * S_KV + (size_t)(tS >> 4) * 4) * DH + (tS & 15) * 4;
  const float* mrow = Mg + (size_t)qrow * S_KV + quad * 4;

  const int swz = l15 & 7;
  const int c0 = (quad ^ swz) * 8;
  const int c1 = ((quad + 4) ^ swz) * 8;

  f32x4 acc[4];
#pragma unroll
  for (int nt = 0; nt < 4; ++nt)
#pragma unroll
    for (int r = 0; r < 4; ++r) acc[nt][r] = 0.0f;
  float rs = 0.0f;

  {
    f32x4 L[4];
    if (isK) {
      L[0] = *(const f32x4*)(sgp);
      L[1] = *(const f32x4*)(sgp + 4);
      L[2] = *(const f32x4*)(sgp + 32 * DH);
      L[3] = *(const f32x4*)(sgp + 32 * DH + 4);
      stageK(&ldsK[0][0], L, tS);
    } else {
#pragma unroll
      for (int i = 0; i < 4; ++i) L[i] = *(const f32x4*)(sgp + i * DH);
      stageV(&ldsV[0][0], L, tS);
    }
  }
  __syncthreads();

  for (int it = 0; it < ITERS; ++it) {
    const int p = it & 1, kv0 = it * BK;
    const bool more = (it + 1 < ITERS);
    const unsigned short* kb = &ldsK[p][l15 * KROW];
    short4v pf[4];
#pragma unroll
    for (int h = 0; h < 4; ++h) {
      const short8 kf0 = *(const short8*)(kb + h * 1024 + c0);
      const short8 kf1 = *(const short8*)(kb + h * 1024 + c1);
      const f32x4 mk = *(const f32x4*)(mrow + kv0 + 16 * h);
      f32x4 c = {0.f, 0.f, 0.f, 0.f};
      c = __builtin_amdgcn_mfma_f32_16x16x32_bf16(kf0, qf0, c, 0, 0, 0);
      c = __builtin_amdgcn_mfma_f32_16x16x32_bf16(kf1, qf1, c, 0, 0, 0);
      float e[4];
#pragma unroll
      for (int r = 0; r < 4; ++r)
        e[r] = __builtin_amdgcn_exp2f(fmaf(mk[r], LOG2E, c[r]));
      rs += (e[0] + e[1]) + (e[2] + e[3]);
      union { uint2v u; short4v s; } ue;
      ue.u[0] = packrne(e[0], e[1]);
      ue.u[1] = packrne(e[2], e[3]);
      pf[h] = ue.s;
    }
    f32x4 L[4];
    if (more) {
      const float* np = sgp + (size_t)(kv0 + BK) * DH;
      if (isK) {
        L[0] = *(const f32x4*)(np);
        L[1] = *(const f32x4*)(np + 4);
        L[2] = *(const f32x4*)(np + 32 * DH);
        L[3] = *(const f32x4*)(np + 32 * DH + 4);
      } else {
#pragma unroll
        for (int i = 0; i < 4; ++i) L[i] = *(const f32x4*)(np + i * DH);
      }
    }
#pragma unroll
    for (int nt = 0; nt < 4; ++nt) {
      const int vcol = l15 + 16 * nt;
      const int xr   = (l15 >> 2) + 4 * nt;
#pragma unroll
      for (int h = 0; h < 4; ++h) {
        const int slot = ((4 * h + quad) + xr) & 15;
        short4v vf = *(const short4v*)&ldsV[p][vcol * VSTR + slot * 4];
        acc[nt] = mfma16(vf, pf[h], acc[nt]);
      }
    }
    if (more) {
      if (isK) stageK(&ldsK[p ^ 1][0], L, tS);
      else     stageV(&ldsV[p ^ 1][0], L, tS);
    }
    __syncthreads();
  }

  rs += __shfl_xor(rs, 16, 64);
  rs += __shfl_xor(rs, 32, 64);
  const float inv = 1.0f / rs;
  float* ob = Og + ((size_t)n * S_Q + (size_t)qrow) * DH + quad * 4;
#pragma unroll
  for (int nt = 0; nt < 4; ++nt) {
    f32x4 o;
#pragma unroll
    for (int r = 0; r < 4; ++r) o[r] = acc[nt][r] * inv;
    *(f32x4*)(ob + 16 * nt) = o;
  }
}

extern "C" void kernel_launch(void* const* d_in, const int* in_sizes, int n_in,
                              void* d_out, int out_size, void* d_ws, size_t ws_size,
                              hipStream_t stream) {
  (void)in_sizes; (void)n_in; (void)out_size;
  const float* q = (const float*)d_in[0];
  const float* k = (const float*)d_in[1];
  const float* v = (const float*)d_in[2];
  const float* m = (const float*)d_in[3];
  float* o = (float*)d_out;

  constexpr size_t IMG_BYTES = (size_t)N_B * 64 * TILE_B;   // 17.8 MB

  if (d_ws != nullptr && ws_size >= IMG_BYTES) {
    // primary: prep + 256-thr 4-blocks/CU single pass
    unsigned short* imgs = (unsigned short*)d_ws;
    hipLaunchKernelGGL(sdpa_prep, dim3(N_B * 64), dim3(256), 0, stream,
                       k, v, imgs);
    dim3 grid(S_Q / BQ, N_B);       // (64, 16) = 1024 blocks x 256 thr
    hipLaunchKernelGGL(sdpa_fwd4, grid, dim3(256), 0, stream,
                       q, m, imgs, o);
  } else {
    // fallback: reg-staging single-pass (512-thr, 2 blocks/CU)
    dim3 grid(S_Q / 128, N_B);
    hipLaunchKernelGGL(sdpa_fwd_reg, grid, dim3(512), 0, stream,
                       q, k, v, m, o);
  }
}